// Round 12
// baseline (806.468 us; speedup 1.0000x reference)
//
#include <hip/hip_runtime.h>
#include <stdint.h>

#define B_ 64
#define T_ 256
#define K_ 48
#define KK 2304
#define START_TAG 46
#define END_TAG 47
#define LOG2E 1.4426950408889634f
#define LN2   0.6931471805599453f
#define ESHIFT 6.0f
#define NEGBIG -1.0e9f
#define POSBIG  1.0e9f

typedef __attribute__((ext_vector_type(4))) float f32x4;
typedef __attribute__((ext_vector_type(8))) short s16x8;

#define EXP2F(x) __builtin_amdgcn_exp2f(x)
#define LOG2F(x) __builtin_amdgcn_logf(x)
#define EX(v) EXP2F(fmaf((v), LOG2E, -ESHIFT))
#define MFMA32(a, b, c) __builtin_amdgcn_mfma_f32_16x16x32_bf16((a), (b), (c), 0, 0, 0)

static __device__ __forceinline__ int cvtpk(float lo, float hi) {
    int r; asm("v_cvt_pk_bf16_f32 %0, %1, %2" : "=v"(r) : "v"(lo), "v"(hi)); return r;
}
static __device__ __forceinline__ s16x8 mk8(int a, int b, int c2, int d) {
    union { int i[4]; s16x8 v; } u; u.i[0] = a; u.i[1] = b; u.i[2] = c2; u.i[3] = d;
    return u.v;
}
static __device__ __forceinline__ float bfr(float x) {   // bf16 RNE round
    int r = cvtpk(x, x);
    return __int_as_float((r & 0xFFFF) << 16);
}

// Raw A values for tile k: chunk0 raw[rt*8+j]=tg[(8L+j)*48+16rt+c] (k-slot 8L+j),
// chunk1 raw[24+rt*4+j]=tg[(32+4L+j)*48+16rt+c] (k-slot j<4 -> k=32+4L+j).
static __device__ __forceinline__ void load_tile(float (&raw)[36], const float* tb,
                                                 int k, int L, int c) {
    const float* tg = tb + (size_t)k * KK;
#pragma unroll
    for (int rt = 0; rt < 3; ++rt) {
#pragma unroll
        for (int j = 0; j < 8; ++j)
            raw[rt * 8 + j] = tg[(8 * L + j) * K_ + 16 * rt + c];
#pragma unroll
        for (int j = 0; j < 4; ++j)
            raw[24 + rt * 4 + j] = tg[(32 + 4 * L + j) * K_ + 16 * rt + c];
    }
}

// self-check: 2 acc entries per lane vs from-global f32 reference (bf16-rounded ops)
static __device__ __noinline__ bool self_check(const f32x4 (&acc)[9],
                                               const float* tg0, const float* tg1,
                                               int L, int c) {
    const int m0 = 4 * L,          c0 = c;        // (rt,ct,r)=(0,0,0)
    const int m1 = 32 + 4 * L + 3, c1 = 16 + c;   // (rt,ct,r)=(2,1,3)
    float ref0 = 0.f, ref1 = 0.f;
#pragma unroll 4
    for (int k = 0; k < K_; ++k) {
        ref0 += bfr(EX(tg1[k * K_ + m0])) * bfr(EX(tg0[c0 * K_ + k]));
        ref1 += bfr(EX(tg1[k * K_ + m1])) * bfr(EX(tg0[c1 * K_ + k]));
    }
    const float a0 = acc[0][0], a1 = acc[2 * 3 + 1][3];
    return (fabsf(ref0 - a0) > 0.03f * fmaxf(fabsf(ref0), 1e-20f)) ||
           (fabsf(ref1 - a1) > 0.03f * fmaxf(fabsf(ref1), 1e-20f));
}

// one product step: A = E_tile^T frags from raw; acc = A x B; D -> LDS P^T -> next B frags
#define STEP(RAW, IDX)                                                             \
  {                                                                                \
    _Pragma("unroll")                                                              \
    for (int rt = 0; rt < 3; ++rt) {                                               \
      aF[rt] = mk8(cvtpk(EX(RAW[rt * 8 + 0]), EX(RAW[rt * 8 + 1])),                \
                   cvtpk(EX(RAW[rt * 8 + 2]), EX(RAW[rt * 8 + 3])),                \
                   cvtpk(EX(RAW[rt * 8 + 4]), EX(RAW[rt * 8 + 5])),                \
                   cvtpk(EX(RAW[rt * 8 + 6]), EX(RAW[rt * 8 + 7])));               \
      aF[3 + rt] = mk8(cvtpk(EX(RAW[24 + rt * 4 + 0]), EX(RAW[24 + rt * 4 + 1])),  \
                       cvtpk(EX(RAW[24 + rt * 4 + 2]), EX(RAW[24 + rt * 4 + 3])),  \
                       0, 0);                                                      \
    }                                                                              \
    _Pragma("unroll")                                                              \
    for (int rt = 0; rt < 3; ++rt)                                                 \
      _Pragma("unroll")                                                            \
      for (int ct = 0; ct < 3; ++ct)                                               \
        acc[rt * 3 + ct] = MFMA32(aF[rt], bF[ct], zf);                             \
    _Pragma("unroll")                                                              \
    for (int rt = 0; rt < 3; ++rt)                                                 \
      _Pragma("unroll")                                                            \
      for (int ct = 0; ct < 3; ++ct)                                               \
        acc[rt * 3 + ct] = MFMA32(aF[3 + rt], bF[3 + ct], acc[rt * 3 + ct]);       \
    if ((IDX) == 1) chkbad = self_check(acc, tb, tb + KK, L, c);                   \
    _Pragma("unroll")                                                              \
    for (int rt = 0; rt < 3; ++rt)                                                 \
      _Pragma("unroll")                                                            \
      for (int ct = 0; ct < 3; ++ct) {                                             \
        int2 w; w.x = cvtpk(acc[rt * 3 + ct].x, acc[rt * 3 + ct].y);               \
        w.y = cvtpk(acc[rt * 3 + ct].z, acc[rt * 3 + ct].w);                       \
        *reinterpret_cast<int2*>(&PT[(16 * ct + c) * 56 + 16 * rt + 4 * L]) = w;   \
      }                                                                            \
    _Pragma("unroll")                                                              \
    for (int ct = 0; ct < 3; ++ct) {                                               \
      const int4 v0 = *reinterpret_cast<const int4*>(&PT[(16 * ct + c) * 56 + 8 * L]); \
      bF[ct] = mk8(v0.x, v0.y, v0.z, v0.w);                                        \
      const int2 v1 = *reinterpret_cast<const int2*>(&PT[(16 * ct + c) * 56 + 32 + 4 * L]); \
      bF[3 + ct] = mk8(v1.x, v1.y, 0, 0);                                          \
    }                                                                              \
  }

// grid 256 = 64 b x 4 segments; ONE wave per block.
// P = E_{n-1}^T ... E_0^T via D = E_i^T x B; B carried through LDS P^T (verified D-map).
__launch_bounds__(64, 1)
__global__ void seg_kernel(const float* __restrict__ scores,
                           const int* __restrict__ lengths,
                           float* __restrict__ wsW,
                           int* __restrict__ flags) {
    __shared__ short PT[48 * 56];   // P^T, bf16, row stride 56 shorts (112 B, 16B-aligned)

    const int bid  = blockIdx.x;
    const int b    = bid >> 2;
    const int seg  = bid & 3;
    const int lane = threadIdx.x;

    int len = lengths[b]; len = min(max(len, 1), T_);
    const int last_t  = len - 1;
    const int segbase = seg * 64;
    const int cap     = (seg == 3) ? 63 : 64;
    const int n       = min(max(last_t - segbase, 0), cap);

    float* Wp = wsW + (size_t)bid * KK;

    if (n == 0) {   // identity transfer in log2 domain
        for (int e = lane; e < KK; e += 64) {
            int m = e / K_, c2 = e - m * K_;
            Wp[e] = (m == c2) ? 0.f : NEGBIG;
        }
        if (lane == 0) flags[bid] = 0;
        return;
    }
    if (n <= 2) {   // short segment: exact fallback in combine
        if (lane == 0) flags[bid] = 3;
        return;
    }

    const float* sb = scores + (size_t)b * T_ * KK;
    const float* tb = sb + (size_t)(segbase + 1) * KK;   // tile k <-> t = segbase+1+k

    const int c = lane & 15, L = lane >> 4;

    // ---- B0 = E_0^T fragments straight from global ----
    s16x8 aF[6], bF[6];
    f32x4 acc[9];
    const f32x4 zf = (f32x4){0.f, 0.f, 0.f, 0.f};
#pragma unroll
    for (int ct = 0; ct < 3; ++ct) {
        const float* r0 = tb + (16 * ct + c) * K_;
        bF[ct] = mk8(cvtpk(EX(r0[8 * L + 0]), EX(r0[8 * L + 1])),
                     cvtpk(EX(r0[8 * L + 2]), EX(r0[8 * L + 3])),
                     cvtpk(EX(r0[8 * L + 4]), EX(r0[8 * L + 5])),
                     cvtpk(EX(r0[8 * L + 6]), EX(r0[8 * L + 7])));
        bF[3 + ct] = mk8(cvtpk(EX(r0[32 + 4 * L + 0]), EX(r0[32 + 4 * L + 1])),
                         cvtpk(EX(r0[32 + 4 * L + 2]), EX(r0[32 + 4 * L + 3])),
                         0, 0);
    }

    bool chkbad = false;
    const int S = n - 1;            // MFMA steps over tiles 1..n-1 (S >= 2)
    float rA[36], rB[36], rC[36];
    load_tile(rA, tb, 1, L, c);
    load_tile(rB, tb, 2, L, c);
    if (3 <= S) load_tile(rC, tb, 3, L, c);

    int t1 = 1;
#pragma unroll 1
    while (t1 + 2 <= S) {
        STEP(rA, t1); if (t1 + 3 <= S) load_tile(rA, tb, t1 + 3, L, c);
        STEP(rB, t1 + 1); if (t1 + 4 <= S) load_tile(rB, tb, t1 + 4, L, c);
        STEP(rC, t1 + 2); if (t1 + 5 <= S) load_tile(rC, tb, t1 + 5, L, c);
        t1 += 3;
    }
    if (t1 <= S)     STEP(rA, t1);
    if (t1 + 1 <= S) STEP(rB, t1 + 1);

    // ---- epilogue: flags + W = clamp(log2(acc)) + 6n  (D-map: col=lane&15, row=4L+r) ----
    const float sh = ESHIFT * (float)n;
    bool rbad = false;
#pragma unroll
    for (int rt = 0; rt < 3; ++rt)
#pragma unroll
        for (int ct = 0; ct < 3; ++ct)
#pragma unroll
            for (int r = 0; r < 4; ++r) {
                const float x = acc[rt * 3 + ct][r];
                rbad = rbad || !(x > 0.f && x < 3.0e38f);
                const float w = fminf(fmaxf(LOG2F(x), NEGBIG), POSBIG);
                Wp[(16 * rt + 4 * L + r) * K_ + 16 * ct + c] = w + sh;
            }
    const bool anychk = __any(chkbad);
    const bool anyr   = __any(rbad);
    if (lane == 0) flags[bid] = anychk ? 2 : (anyr ? 1 : 0);
}

// grid 64 (one per b), block 64: compose init with 4 segment matrices + gold.
// Flagged segments recomputed exactly (scalar LSE per step, proven R9-R11).
__global__ void combine_kernel(const float* __restrict__ scores,
                               const int* __restrict__ targets,
                               const int* __restrict__ lengths,
                               const float* __restrict__ wsW,
                               const int* __restrict__ flags,
                               float* __restrict__ losses) {
    __shared__ float vsh[K_];
    __shared__ __align__(16) float tile[KK];
    const int b = blockIdx.x;
    const int j = threadIdx.x;
    int len = lengths[b]; len = min(max(len, 1), T_);
    const int last_t = len - 1;
    const float* sb = scores + (size_t)b * T_ * KK;

    float g = 0.f;
#pragma unroll
    for (int r = 0; r < 4; ++r) {
        int t = j + 64 * r;
        if (t < len) g += sb[(size_t)t * KK + targets[b * T_ + t]];
    }
#pragma unroll
    for (int off = 1; off < 64; off <<= 1) g += __shfl_xor(g, off);

    float v = (j < K_) ? sb[START_TAG * K_ + j] * LOG2E : 0.f;   // log2 units

#pragma unroll 1
    for (int s = 0; s < 4; ++s) {
        const int cap = (s == 3) ? 63 : 64;
        const int ns  = min(max(last_t - 64 * s, 0), cap);
        if (ns == 0) continue;
        const int flag = flags[b * 4 + s];

        __syncthreads();
        if (j < K_) vsh[j] = v;
        __syncthreads();

        if (!flag) {
            if (j < K_) {
                const float* Wr = wsW + (size_t)(b * 4 + s) * KK + j * K_;
                float m = -3.0e38f;
                float xs[K_];
#pragma unroll
                for (int c = 0; c < K_; ++c) { xs[c] = vsh[c] + Wr[c]; m = fmaxf(m, xs[c]); }
                float ssum = 0.f;
#pragma unroll
                for (int c = 0; c < K_; ++c) ssum += EXP2F(xs[c] - m);
                v = m + LOG2F(ssum);
            }
        } else {
#pragma unroll 1
            for (int k = 0; k < ns; ++k) {
                const float* st = sb + (size_t)(64 * s + 1 + k) * KK;
                for (int q = j; q < KK / 4; q += 64)
                    ((float4*)tile)[q] = ((const float4*)st)[q];
                __syncthreads();
                float vn = 0.f;
                if (j < K_) {
                    float m = -3.0e38f;
#pragma unroll
                    for (int i2 = 0; i2 < K_; ++i2)
                        m = fmaxf(m, vsh[i2] + tile[i2 * K_ + j] * LOG2E);
                    float ssum = 0.f;
#pragma unroll
                    for (int i2 = 0; i2 < K_; ++i2)
                        ssum += EXP2F(vsh[i2] + tile[i2 * K_ + j] * LOG2E - m);
                    vn = m + LOG2F(ssum);
                }
                __syncthreads();
                if (j < K_) vsh[j] = vn;
                __syncthreads();
            }
            if (j < K_) v = vsh[j];
        }
    }

    float vEnd = __shfl(v, END_TAG);
    if (j == 0) losses[b] = LN2 * vEnd - g;
}

__global__ void reduce_kernel(const float* __restrict__ losses, float* __restrict__ out) {
    float v = losses[threadIdx.x];
#pragma unroll
    for (int off = 1; off < 64; off <<= 1) v += __shfl_xor(v, off);
    if (threadIdx.x == 0) out[0] = v * (1.0f / 64.0f);
}

extern "C" void kernel_launch(void* const* d_in, const int* in_sizes, int n_in,
                              void* d_out, int out_size, void* d_ws, size_t ws_size,
                              hipStream_t stream) {
    const float* scores  = (const float*)d_in[0];
    const int*   targets = (const int*)d_in[1];
    const int*   lengths = (const int*)d_in[2];
    float* wsW    = (float*)d_ws;                 // 256 * 2304 floats
    float* losses = wsW + 256 * KK;               // + 64 floats
    int*   flags  = (int*)(losses + 64);          // + 256 ints

    seg_kernel<<<dim3(256), dim3(64), 0, stream>>>(scores, lengths, wsW, flags);
    combine_kernel<<<dim3(64), dim3(64), 0, stream>>>(scores, targets, lengths, wsW, flags, losses);
    reduce_kernel<<<dim3(1), dim3(64), 0, stream>>>(losses, (float*)d_out);
}